// Round 3
// baseline (979.698 us; speedup 1.0000x reference)
//
#include <hip/hip_runtime.h>

typedef __bf16 bf16x8 __attribute__((ext_vector_type(8)));
typedef __bf16 bf16x4 __attribute__((ext_vector_type(4)));
typedef float  f32x4  __attribute__((ext_vector_type(4)));

#define MFMA_BF16(a, b, c) __builtin_amdgcn_mfma_f32_16x16x32_bf16((a), (b), (c), 0, 0, 0)

static constexpr int BATCH  = 2;
static constexpr int HEADS  = 12;
static constexpr int SEQ    = 2048;
static constexpr int DHEAD  = 64;
static constexpr int DMODEL = 768;
static constexpr int M_ROWS = BATCH * SEQ;                     // 4096
static constexpr int OUT_ELEMS  = M_ROWS * DMODEL;             // 3145728
static constexpr int HEAD_ELEMS = BATCH * HEADS * SEQ * DHEAD; // 3145728

__device__ __forceinline__ void split_bf16(float x, __bf16 &hi, __bf16 &lo) {
    __bf16 h = (__bf16)x;
    hi = h;
    lo = (__bf16)(x - (float)h);
}

// ---------------------------------------------------------------------------
// K1: fused QKV projection.  out = X @ W.T + b, split to bf16 hi/lo.
//  z=0: Q (scaled 1/8), layout [b,h,s,d], hi+lo
//  z=1: K full rows      [b,h,s,d], hi+lo
//  z=2: V transposed     [b,h,d,s], hi only
// ---------------------------------------------------------------------------
__global__ __launch_bounds__(256) void qkv_proj_kernel(
    const float* __restrict__ qin, const float* __restrict__ kin, const float* __restrict__ vin,
    const float* __restrict__ Wq, const float* __restrict__ bq,
    const float* __restrict__ Wk, const float* __restrict__ bk,
    const float* __restrict__ Wv, const float* __restrict__ bv,
    __bf16* __restrict__ Qh_hi, __bf16* __restrict__ Qh_lo,
    __bf16* __restrict__ Kh_hi, __bf16* __restrict__ Kh_lo,
    __bf16* __restrict__ Vh)
{
    const int z = blockIdx.z;
    const float* X; const float* W; const float* bias;
    float scale = 1.0f;
    if (z == 0)      { X = qin; W = Wq; bias = bq; scale = 0.125f; }
    else if (z == 1) { X = kin; W = Wk; bias = bk; }
    else             { X = vin; W = Wv; bias = bv; }

    __shared__ __bf16 As_hi[128 * 40];
    __shared__ __bf16 As_lo[128 * 40];
    __shared__ __bf16 Bs_hi[128 * 40];
    __shared__ __bf16 Bs_lo[128 * 40];

    const int tid  = threadIdx.x;
    const int wid  = tid >> 6;
    const int lane = tid & 63;
    const int quad = lane >> 4;
    const int l15  = lane & 15;
    const int wm = (wid >> 1) * 64;
    const int wn = (wid & 1) * 64;
    const int mbase = blockIdx.x * 128;
    const int nbase = blockIdx.y * 128;

    const f32x4 zf = {0.f, 0.f, 0.f, 0.f};
    f32x4 acc[4][4];
    #pragma unroll
    for (int i = 0; i < 4; i++)
        #pragma unroll
        for (int j = 0; j < 4; j++) acc[i][j] = zf;

    for (int k0 = 0; k0 < DMODEL; k0 += 32) {
        #pragma unroll
        for (int i = 0; i < 4; i++) {
            int idx = i * 256 + tid;
            int r = idx >> 3;
            int c = (idx & 7) * 4;
            float4 a4 = *(const float4*)&X[(size_t)(mbase + r) * DMODEL + k0 + c];
            float4 b4 = *(const float4*)&W[(size_t)(nbase + r) * DMODEL + k0 + c];
            float af[4] = {a4.x, a4.y, a4.z, a4.w};
            float bf[4] = {b4.x, b4.y, b4.z, b4.w};
            bf16x4 ah4, al4, bh4, bl4;
            #pragma unroll
            for (int j = 0; j < 4; j++) {
                __bf16 hi, lo;
                split_bf16(af[j], hi, lo); ah4[j] = hi; al4[j] = lo;
                split_bf16(bf[j], hi, lo); bh4[j] = hi; bl4[j] = lo;
            }
            *(bf16x4*)&As_hi[r * 40 + c] = ah4;
            *(bf16x4*)&As_lo[r * 40 + c] = al4;
            *(bf16x4*)&Bs_hi[r * 40 + c] = bh4;
            *(bf16x4*)&Bs_lo[r * 40 + c] = bl4;
        }
        __syncthreads();

        bf16x8 ah[4], al[4], bh[4], bl[4];
        #pragma unroll
        for (int f = 0; f < 4; f++) {
            int ra = (wm + f * 16 + l15) * 40 + quad * 8;
            ah[f] = *(const bf16x8*)&As_hi[ra];
            al[f] = *(const bf16x8*)&As_lo[ra];
            int rb = (wn + f * 16 + l15) * 40 + quad * 8;
            bh[f] = *(const bf16x8*)&Bs_hi[rb];
            bl[f] = *(const bf16x8*)&Bs_lo[rb];
        }
        #pragma unroll
        for (int fi = 0; fi < 4; fi++)
            #pragma unroll
            for (int fj = 0; fj < 4; fj++) {
                acc[fi][fj] = MFMA_BF16(ah[fi], bh[fj], acc[fi][fj]);
                acc[fi][fj] = MFMA_BF16(ah[fi], bl[fj], acc[fi][fj]);
                acc[fi][fj] = MFMA_BF16(al[fi], bh[fj], acc[fi][fj]);
            }
        __syncthreads();
    }

    float bvals[4];
    #pragma unroll
    for (int fj = 0; fj < 4; fj++)
        bvals[fj] = bias[nbase + wn + fj * 16 + l15];

    #pragma unroll
    for (int fi = 0; fi < 4; fi++)
        #pragma unroll
        for (int fj = 0; fj < 4; fj++)
            #pragma unroll
            for (int r = 0; r < 4; r++) {
                int m = mbase + wm + fi * 16 + quad * 4 + r;
                int n = nbase + wn + fj * 16 + l15;
                float val = (acc[fi][fj][r] + bvals[fj]) * scale;
                __bf16 hi, lo;
                split_bf16(val, hi, lo);
                int bb = m >> 11;
                int s  = m & (SEQ - 1);
                int hh = n >> 6;
                int d  = n & 63;
                int bh_ = bb * HEADS + hh;
                if (z == 0) {
                    size_t idx = ((size_t)bh_ * SEQ + s) * DHEAD + d;
                    Qh_hi[idx] = hi; Qh_lo[idx] = lo;
                } else if (z == 1) {
                    size_t idx = ((size_t)bh_ * SEQ + s) * DHEAD + d;
                    Kh_hi[idx] = hi; Kh_lo[idx] = lo;
                } else {
                    size_t idx = ((size_t)bh_ * DHEAD + d) * SEQ + s;
                    Vh[idx] = hi;
                }
            }
}

// ---------------------------------------------------------------------------
// K2a: attention ctx + row sums.  64 q-rows per block, 4 waves x 16 rows.
// NO K/V LDS staging: MFMA fragments load straight from global (fully
// coalesced 1KB/wave loads, K/V is L2-resident per head).  Ps is a
// per-wave-PRIVATE LDS stripe -> no __syncthreads in the K-loop at all.
// ---------------------------------------------------------------------------
__global__ __launch_bounds__(256) void attn_ctx_kernel(
    const __bf16* __restrict__ Qh_hi, const __bf16* __restrict__ Qh_lo,
    const __bf16* __restrict__ Kh_hi, const __bf16* __restrict__ Kh_lo,
    const __bf16* __restrict__ Vh,
    const float* __restrict__ mask,
    float* __restrict__ ctx,       // [B,S,DMODEL]
    float* __restrict__ lsum)      // [B,H,S]
{
    const int qt = blockIdx.x;
    const int h  = blockIdx.y;
    const int b  = blockIdx.z;
    const int bh = b * HEADS + h;

    const int tid  = threadIdx.x;
    const int wid  = tid >> 6;
    const int lane = tid & 63;
    const int quad = lane >> 4;
    const int l15  = lane & 15;
    const int qrow0 = qt * 64 + wid * 16;

    __shared__ __bf16 Ps[64 * 72];     // per-wave-private 16-row stripes
    __shared__ float bias_s[SEQ];

    for (int i = tid; i < SEQ; i += 256)
        bias_s[i] = (mask[b * SEQ + i] != 0.0f) ? -1e30f : 0.0f;
    __syncthreads();

    const __bf16* Kh_hi_b = Kh_hi + (size_t)bh * SEQ * DHEAD;
    const __bf16* Kh_lo_b = Kh_lo + (size_t)bh * SEQ * DHEAD;
    const __bf16* Vh_b    = Vh    + (size_t)bh * DHEAD * SEQ;

    // Q fragments for this wave's 16 rows (hi/lo, 64-d split in two 32-chunks)
    bf16x8 aqh[2], aql[2];
    #pragma unroll
    for (int ks = 0; ks < 2; ks++) {
        size_t off = ((size_t)bh * SEQ + qrow0 + l15) * DHEAD + ks * 32 + quad * 8;
        aqh[ks] = *(const bf16x8*)&Qh_hi[off];
        aql[ks] = *(const bf16x8*)&Qh_lo[off];
    }

    const f32x4 zf = {0.f, 0.f, 0.f, 0.f};
    f32x4 cacc[4];
    #pragma unroll
    for (int fj = 0; fj < 4; fj++) cacc[fj] = zf;
    float lrun[4] = {};

    for (int kt = 0; kt < SEQ / 64; kt++) {
        const int k0 = kt * 64;

        // QK^T (q pre-scaled by 1/8), K fragments direct from global
        f32x4 sacc[4];
        #pragma unroll
        for (int fj = 0; fj < 4; fj++) sacc[fj] = zf;

        #pragma unroll
        for (int ks = 0; ks < 2; ks++) {
            bf16x8 kh[4], kl[4];
            #pragma unroll
            for (int fj = 0; fj < 4; fj++) {
                size_t off = (size_t)(k0 + fj * 16 + l15) * DHEAD + ks * 32 + quad * 8;
                kh[fj] = *(const bf16x8*)&Kh_hi_b[off];
                kl[fj] = *(const bf16x8*)&Kh_lo_b[off];
            }
            #pragma unroll
            for (int fj = 0; fj < 4; fj++) {
                sacc[fj] = MFMA_BF16(aqh[ks], kh[fj], sacc[fj]);
                sacc[fj] = MFMA_BF16(aqh[ks], kl[fj], sacc[fj]);
                sacc[fj] = MFMA_BF16(aql[ks], kh[fj], sacc[fj]);
            }
        }

        // p~ = exp(s + bias); bf16 p~ to this wave's Ps stripe, row sums
        float tsum[4] = {};
        #pragma unroll
        for (int fj = 0; fj < 4; fj++) {
            float bias = bias_s[k0 + fj * 16 + l15];
            #pragma unroll
            for (int r = 0; r < 4; r++) {
                float s = sacc[fj][r] + bias;
                s = fminf(s, 80.0f);
                float p = __expf(s);
                Ps[(wid * 16 + quad * 4 + r) * 72 + fj * 16 + l15] = (__bf16)p;
                tsum[r] += p;
            }
        }
        #pragma unroll
        for (int r = 0; r < 4; r++) {
            float t = tsum[r];
            t += __shfl_xor(t, 1);
            t += __shfl_xor(t, 2);
            t += __shfl_xor(t, 4);
            t += __shfl_xor(t, 8);
            lrun[r] += t;
        }

        // in-wave LDS handoff: DS pipe is in-order per wave; fence the
        // scheduler so reads aren't hoisted above the writes.
        __builtin_amdgcn_sched_barrier(0);

        // PV: A = this wave's Ps rows, B = V^T fragments direct from global
        #pragma unroll
        for (int ks = 0; ks < 2; ks++) {
            bf16x8 ph = *(const bf16x8*)&Ps[(wid * 16 + l15) * 72 + ks * 32 + quad * 8];
            #pragma unroll
            for (int fj = 0; fj < 4; fj++) {
                size_t off = (size_t)(fj * 16 + l15) * SEQ + k0 + ks * 32 + quad * 8;
                bf16x8 vh = *(const bf16x8*)&Vh_b[off];
                cacc[fj] = MFMA_BF16(ph, vh, cacc[fj]);
            }
        }
        __builtin_amdgcn_sched_barrier(0);  // next-iter Ps writes stay below
    }

    #pragma unroll
    for (int r = 0; r < 4; r++) {
        int rl_ = quad * 4 + r;
        int row = qrow0 + rl_;
        float lv = lrun[r];
        if (l15 == 0)
            lsum[(size_t)bh * SEQ + row] = lv;
        float inv = 1.0f / lv;
        #pragma unroll
        for (int fj = 0; fj < 4; fj++)
            ctx[((size_t)b * SEQ + row) * DMODEL + h * DHEAD + fj * 16 + l15] =
                cacc[fj][r] * inv;
    }
}

// ---------------------------------------------------------------------------
// K2b: weights writer.  Recomputes QK^T+exp (bit-identical 3-MFMA split),
// scales by 1/lsum, writes full normalized rows.  NO LDS staging, NO
// barriers in the loop -> pure dataflow, compiler pipelines the loads;
// should sit near the 402MB write-BW floor.
// ---------------------------------------------------------------------------
__global__ __launch_bounds__(256) void attn_weights_kernel(
    const __bf16* __restrict__ Qh_hi, const __bf16* __restrict__ Qh_lo,
    const __bf16* __restrict__ Kh_hi, const __bf16* __restrict__ Kh_lo,
    const float* __restrict__ mask,
    const float* __restrict__ lsum,
    float* __restrict__ wout)      // [B,H,S,S]
{
    const int qt = blockIdx.x;
    const int h  = blockIdx.y;
    const int b  = blockIdx.z;
    const int bh = b * HEADS + h;

    const int tid  = threadIdx.x;
    const int wid  = tid >> 6;
    const int lane = tid & 63;
    const int quad = lane >> 4;
    const int l15  = lane & 15;
    const int qrow0 = qt * 64 + wid * 16;

    __shared__ float bias_s[SEQ];
    for (int i = tid; i < SEQ; i += 256)
        bias_s[i] = (mask[b * SEQ + i] != 0.0f) ? -1e30f : 0.0f;
    __syncthreads();

    const __bf16* Kh_hi_b = Kh_hi + (size_t)bh * SEQ * DHEAD;
    const __bf16* Kh_lo_b = Kh_lo + (size_t)bh * SEQ * DHEAD;

    bf16x8 aqh[2], aql[2];
    #pragma unroll
    for (int ks = 0; ks < 2; ks++) {
        size_t off = ((size_t)bh * SEQ + qrow0 + l15) * DHEAD + ks * 32 + quad * 8;
        aqh[ks] = *(const bf16x8*)&Qh_hi[off];
        aql[ks] = *(const bf16x8*)&Qh_lo[off];
    }

    float inv[4];
    #pragma unroll
    for (int r = 0; r < 4; r++)
        inv[r] = 1.0f / lsum[(size_t)bh * SEQ + qrow0 + quad * 4 + r];

    const f32x4 zf = {0.f, 0.f, 0.f, 0.f};

    for (int kt = 0; kt < SEQ / 64; kt++) {
        const int k0 = kt * 64;

        f32x4 sacc[4];
        #pragma unroll
        for (int fj = 0; fj < 4; fj++) sacc[fj] = zf;

        #pragma unroll
        for (int ks = 0; ks < 2; ks++) {
            bf16x8 kh[4], kl[4];
            #pragma unroll
            for (int fj = 0; fj < 4; fj++) {
                size_t off = (size_t)(k0 + fj * 16 + l15) * DHEAD + ks * 32 + quad * 8;
                kh[fj] = *(const bf16x8*)&Kh_hi_b[off];
                kl[fj] = *(const bf16x8*)&Kh_lo_b[off];
            }
            #pragma unroll
            for (int fj = 0; fj < 4; fj++) {
                sacc[fj] = MFMA_BF16(aqh[ks], kh[fj], sacc[fj]);
                sacc[fj] = MFMA_BF16(aqh[ks], kl[fj], sacc[fj]);
                sacc[fj] = MFMA_BF16(aql[ks], kh[fj], sacc[fj]);
            }
        }

        #pragma unroll
        for (int fj = 0; fj < 4; fj++) {
            float bias = bias_s[k0 + fj * 16 + l15];
            #pragma unroll
            for (int r = 0; r < 4; r++) {
                float s = sacc[fj][r] + bias;
                s = fminf(s, 80.0f);
                float p = __expf(s);
                int row = qrow0 + quad * 4 + r;
                wout[((size_t)bh * SEQ + row) * SEQ + k0 + fj * 16 + l15] = p * inv[r];
            }
        }
    }
}

// ---------------------------------------------------------------------------
// K4: output projection: out = ctx @ Wo.T + bo  (f32 out)
// ---------------------------------------------------------------------------
__global__ __launch_bounds__(256) void out_proj_kernel(
    const float* __restrict__ X, const float* __restrict__ W, const float* __restrict__ bias,
    float* __restrict__ out)
{
    __shared__ __bf16 As_hi[128 * 40];
    __shared__ __bf16 As_lo[128 * 40];
    __shared__ __bf16 Bs_hi[128 * 40];
    __shared__ __bf16 Bs_lo[128 * 40];

    const int tid  = threadIdx.x;
    const int wid  = tid >> 6;
    const int lane = tid & 63;
    const int quad = lane >> 4;
    const int l15  = lane & 15;
    const int wm = (wid >> 1) * 64;
    const int wn = (wid & 1) * 64;
    const int mbase = blockIdx.x * 128;
    const int nbase = blockIdx.y * 128;

    const f32x4 zf = {0.f, 0.f, 0.f, 0.f};
    f32x4 acc[4][4];
    #pragma unroll
    for (int i = 0; i < 4; i++)
        #pragma unroll
        for (int j = 0; j < 4; j++) acc[i][j] = zf;

    for (int k0 = 0; k0 < DMODEL; k0 += 32) {
        #pragma unroll
        for (int i = 0; i < 4; i++) {
            int idx = i * 256 + tid;
            int r = idx >> 3;
            int c = (idx & 7) * 4;
            float4 a4 = *(const float4*)&X[(size_t)(mbase + r) * DMODEL + k0 + c];
            float4 b4 = *(const float4*)&W[(size_t)(nbase + r) * DMODEL + k0 + c];
            float af[4] = {a4.x, a4.y, a4.z, a4.w};
            float bf[4] = {b4.x, b4.y, b4.z, b4.w};
            bf16x4 ah4, al4, bh4, bl4;
            #pragma unroll
            for (int j = 0; j < 4; j++) {
                __bf16 hi, lo;
                split_bf16(af[j], hi, lo); ah4[j] = hi; al4[j] = lo;
                split_bf16(bf[j], hi, lo); bh4[j] = hi; bl4[j] = lo;
            }
            *(bf16x4*)&As_hi[r * 40 + c] = ah4;
            *(bf16x4*)&As_lo[r * 40 + c] = al4;
            *(bf16x4*)&Bs_hi[r * 40 + c] = bh4;
            *(bf16x4*)&Bs_lo[r * 40 + c] = bl4;
        }
        __syncthreads();

        bf16x8 ah[4], al[4], bh[4], bl[4];
        #pragma unroll
        for (int f = 0; f < 4; f++) {
            int ra = (wm + f * 16 + l15) * 40 + quad * 8;
            ah[f] = *(const bf16x8*)&As_hi[ra];
            al[f] = *(const bf16x8*)&As_lo[ra];
            int rb = (wn + f * 16 + l15) * 40 + quad * 8;
            bh[f] = *(const bf16x8*)&Bs_hi[rb];
            bl[f] = *(const bf16x8*)&Bs_lo[rb];
        }
        #pragma unroll
        for (int fi = 0; fi < 4; fi++)
            #pragma unroll
            for (int fj = 0; fj < 4; fj++) {
                acc[fi][fj] = MFMA_BF16(ah[fi], bh[fj], acc[fi][fj]);
                acc[fi][fj] = MFMA_BF16(ah[fi], bl[fj], acc[fi][fj]);
                acc[fi][fj] = MFMA_BF16(al[fi], bh[fj], acc[fi][fj]);
            }
        __syncthreads();
    }

    float bvals[4];
    #pragma unroll
    for (int fj = 0; fj < 4; fj++)
        bvals[fj] = bias[nbase + wn + fj * 16 + l15];

    #pragma unroll
    for (int fi = 0; fi < 4; fi++)
        #pragma unroll
        for (int fj = 0; fj < 4; fj++)
            #pragma unroll
            for (int r = 0; r < 4; r++) {
                int m = mbase + wm + fi * 16 + quad * 4 + r;
                int n = nbase + wn + fj * 16 + l15;
                out[(size_t)m * DMODEL + n] = acc[fi][fj][r] + bvals[fj];
            }
}

// ---------------------------------------------------------------------------
extern "C" void kernel_launch(void* const* d_in, const int* in_sizes, int n_in,
                              void* d_out, int out_size, void* d_ws, size_t ws_size,
                              hipStream_t stream) {
    (void)in_sizes; (void)n_in; (void)out_size; (void)ws_size;

    const float* q    = (const float*)d_in[0];
    const float* k    = (const float*)d_in[1];
    const float* v    = (const float*)d_in[2];
    const float* mask = (const float*)d_in[3];
    const float* Wq   = (const float*)d_in[4];
    const float* bq   = (const float*)d_in[5];
    const float* Wk   = (const float*)d_in[6];
    const float* bk   = (const float*)d_in[7];
    const float* Wv   = (const float*)d_in[8];
    const float* bv   = (const float*)d_in[9];
    const float* Wo   = (const float*)d_in[10];
    const float* bo   = (const float*)d_in[11];

    float* out  = (float*)d_out;
    float* wout = out + (size_t)OUT_ELEMS;     // weights region of d_out

    // workspace layout (~44.2 MB):
    __bf16* wsb = (__bf16*)d_ws;
    __bf16* Qh_hi = wsb;
    __bf16* Qh_lo = wsb + 1 * (size_t)HEAD_ELEMS;
    __bf16* Kh_hi = wsb + 2 * (size_t)HEAD_ELEMS;
    __bf16* Kh_lo = wsb + 3 * (size_t)HEAD_ELEMS;
    __bf16* Vh    = wsb + 4 * (size_t)HEAD_ELEMS;
    float*  ctx   = (float*)(wsb + 5 * (size_t)HEAD_ELEMS);
    float*  lsum  = ctx + (size_t)OUT_ELEMS;

    qkv_proj_kernel<<<dim3(32, 6, 3), 256, 0, stream>>>(
        q, k, v, Wq, bq, Wk, bk, Wv, bv,
        Qh_hi, Qh_lo, Kh_hi, Kh_lo, Vh);

    attn_ctx_kernel<<<dim3(32, 12, 2), 256, 0, stream>>>(
        Qh_hi, Qh_lo, Kh_hi, Kh_lo, Vh, mask, ctx, lsum);

    attn_weights_kernel<<<dim3(32, 12, 2), 256, 0, stream>>>(
        Qh_hi, Qh_lo, Kh_hi, Kh_lo, mask, lsum, wout);

    out_proj_kernel<<<dim3(32, 6, 1), 256, 0, stream>>>(ctx, Wo, bo, out);
}

// Round 4
// 723.214 us; speedup vs baseline: 1.3546x; 1.3546x over previous
//
#include <hip/hip_runtime.h>

typedef __bf16 bf16x8 __attribute__((ext_vector_type(8)));
typedef __bf16 bf16x4 __attribute__((ext_vector_type(4)));
typedef float  f32x4  __attribute__((ext_vector_type(4)));

#define MFMA_BF16(a, b, c) __builtin_amdgcn_mfma_f32_16x16x32_bf16((a), (b), (c), 0, 0, 0)

static constexpr int BATCH  = 2;
static constexpr int HEADS  = 12;
static constexpr int SEQ    = 2048;
static constexpr int DHEAD  = 64;
static constexpr int DMODEL = 768;
static constexpr int M_ROWS = BATCH * SEQ;                     // 4096
static constexpr int OUT_ELEMS  = M_ROWS * DMODEL;             // 3145728
static constexpr int HEAD_ELEMS = BATCH * HEADS * SEQ * DHEAD; // 3145728

__device__ __forceinline__ void split_bf16(float x, __bf16 &hi, __bf16 &lo) {
    __bf16 h = (__bf16)x;
    hi = h;
    lo = (__bf16)(x - (float)h);
}

// ---------------------------------------------------------------------------
// K1: fused QKV projection.  out = X @ W.T + b, split to bf16 hi/lo.
//  z=0: Q (scaled 1/8), layout [b,h,s,d], hi+lo
//  z=1: K full rows      [b,h,s,d], hi+lo
//  z=2: V transposed     [b,h,d,s], hi only
// ---------------------------------------------------------------------------
__global__ __launch_bounds__(256) void qkv_proj_kernel(
    const float* __restrict__ qin, const float* __restrict__ kin, const float* __restrict__ vin,
    const float* __restrict__ Wq, const float* __restrict__ bq,
    const float* __restrict__ Wk, const float* __restrict__ bk,
    const float* __restrict__ Wv, const float* __restrict__ bv,
    __bf16* __restrict__ Qh_hi, __bf16* __restrict__ Qh_lo,
    __bf16* __restrict__ Kh_hi, __bf16* __restrict__ Kh_lo,
    __bf16* __restrict__ Vh)
{
    const int z = blockIdx.z;
    const float* X; const float* W; const float* bias;
    float scale = 1.0f;
    if (z == 0)      { X = qin; W = Wq; bias = bq; scale = 0.125f; }
    else if (z == 1) { X = kin; W = Wk; bias = bk; }
    else             { X = vin; W = Wv; bias = bv; }

    __shared__ __bf16 As_hi[128 * 40];
    __shared__ __bf16 As_lo[128 * 40];
    __shared__ __bf16 Bs_hi[128 * 40];
    __shared__ __bf16 Bs_lo[128 * 40];

    const int tid  = threadIdx.x;
    const int wid  = tid >> 6;
    const int lane = tid & 63;
    const int quad = lane >> 4;
    const int l15  = lane & 15;
    const int wm = (wid >> 1) * 64;
    const int wn = (wid & 1) * 64;
    const int mbase = blockIdx.x * 128;
    const int nbase = blockIdx.y * 128;

    const f32x4 zf = {0.f, 0.f, 0.f, 0.f};
    f32x4 acc[4][4];
    #pragma unroll
    for (int i = 0; i < 4; i++)
        #pragma unroll
        for (int j = 0; j < 4; j++) acc[i][j] = zf;

    for (int k0 = 0; k0 < DMODEL; k0 += 32) {
        #pragma unroll
        for (int i = 0; i < 4; i++) {
            int idx = i * 256 + tid;
            int r = idx >> 3;
            int c = (idx & 7) * 4;
            float4 a4 = *(const float4*)&X[(size_t)(mbase + r) * DMODEL + k0 + c];
            float4 b4 = *(const float4*)&W[(size_t)(nbase + r) * DMODEL + k0 + c];
            float af[4] = {a4.x, a4.y, a4.z, a4.w};
            float bf[4] = {b4.x, b4.y, b4.z, b4.w};
            bf16x4 ah4, al4, bh4, bl4;
            #pragma unroll
            for (int j = 0; j < 4; j++) {
                __bf16 hi, lo;
                split_bf16(af[j], hi, lo); ah4[j] = hi; al4[j] = lo;
                split_bf16(bf[j], hi, lo); bh4[j] = hi; bl4[j] = lo;
            }
            *(bf16x4*)&As_hi[r * 40 + c] = ah4;
            *(bf16x4*)&As_lo[r * 40 + c] = al4;
            *(bf16x4*)&Bs_hi[r * 40 + c] = bh4;
            *(bf16x4*)&Bs_lo[r * 40 + c] = bl4;
        }
        __syncthreads();

        bf16x8 ah[4], al[4], bh[4], bl[4];
        #pragma unroll
        for (int f = 0; f < 4; f++) {
            int ra = (wm + f * 16 + l15) * 40 + quad * 8;
            ah[f] = *(const bf16x8*)&As_hi[ra];
            al[f] = *(const bf16x8*)&As_lo[ra];
            int rb = (wn + f * 16 + l15) * 40 + quad * 8;
            bh[f] = *(const bf16x8*)&Bs_hi[rb];
            bl[f] = *(const bf16x8*)&Bs_lo[rb];
        }
        #pragma unroll
        for (int fi = 0; fi < 4; fi++)
            #pragma unroll
            for (int fj = 0; fj < 4; fj++) {
                acc[fi][fj] = MFMA_BF16(ah[fi], bh[fj], acc[fi][fj]);
                acc[fi][fj] = MFMA_BF16(ah[fi], bl[fj], acc[fi][fj]);
                acc[fi][fj] = MFMA_BF16(al[fi], bh[fj], acc[fi][fj]);
            }
        __syncthreads();
    }

    float bvals[4];
    #pragma unroll
    for (int fj = 0; fj < 4; fj++)
        bvals[fj] = bias[nbase + wn + fj * 16 + l15];

    #pragma unroll
    for (int fi = 0; fi < 4; fi++)
        #pragma unroll
        for (int fj = 0; fj < 4; fj++)
            #pragma unroll
            for (int r = 0; r < 4; r++) {
                int m = mbase + wm + fi * 16 + quad * 4 + r;
                int n = nbase + wn + fj * 16 + l15;
                float val = (acc[fi][fj][r] + bvals[fj]) * scale;
                __bf16 hi, lo;
                split_bf16(val, hi, lo);
                int bb = m >> 11;
                int s  = m & (SEQ - 1);
                int hh = n >> 6;
                int d  = n & 63;
                int bh_ = bb * HEADS + hh;
                if (z == 0) {
                    size_t idx = ((size_t)bh_ * SEQ + s) * DHEAD + d;
                    Qh_hi[idx] = hi; Qh_lo[idx] = lo;
                } else if (z == 1) {
                    size_t idx = ((size_t)bh_ * SEQ + s) * DHEAD + d;
                    Kh_hi[idx] = hi; Kh_lo[idx] = lo;
                } else {
                    size_t idx = ((size_t)bh_ * DHEAD + d) * SEQ + s;
                    Vh[idx] = hi;
                }
            }
}

// ---------------------------------------------------------------------------
// K2a: attention ctx + row sums.  Round-2 staged structure + T14 async-STAGE
// split: tile t+1's global loads are ISSUED right after the barrier that
// publishes tile t, and consumed (regs->LDS) only at the top of the next
// iteration -- HBM/L2 latency hides under the whole QK/softmax/PV phase.
// ---------------------------------------------------------------------------
__global__ __launch_bounds__(256) void attn_ctx_kernel(
    const __bf16* __restrict__ Qh_hi, const __bf16* __restrict__ Qh_lo,
    const __bf16* __restrict__ Kh_hi, const __bf16* __restrict__ Kh_lo,
    const __bf16* __restrict__ Vh,
    const float* __restrict__ mask,
    float* __restrict__ ctx,       // [B,S,DMODEL]
    float* __restrict__ lsum)      // [B,H,S]
{
    const int qt = blockIdx.x;
    const int h  = blockIdx.y;
    const int b  = blockIdx.z;
    const int bh = b * HEADS + h;

    const int tid  = threadIdx.x;
    const int wid  = tid >> 6;
    const int lane = tid & 63;
    const int quad = lane >> 4;
    const int l15  = lane & 15;
    const int qrow0 = qt * 64 + wid * 16;

    __shared__ __bf16 Ks_hi[64 * 72];
    __shared__ __bf16 Ks_lo[64 * 72];
    __shared__ __bf16 Vs[64 * 72];
    __shared__ __bf16 Ps[64 * 72];
    __shared__ float bias_s[SEQ];

    for (int i = tid; i < SEQ; i += 256)
        bias_s[i] = (mask[b * SEQ + i] != 0.0f) ? -1e30f : 0.0f;

    const __bf16* Kh_hi_b = Kh_hi + (size_t)bh * SEQ * DHEAD;
    const __bf16* Kh_lo_b = Kh_lo + (size_t)bh * SEQ * DHEAD;
    const __bf16* Vh_b    = Vh    + (size_t)bh * DHEAD * SEQ;

    // Q fragments for this wave's 16 rows (hi/lo, 64-d split in two 32-chunks)
    bf16x8 aqh[2], aql[2];
    #pragma unroll
    for (int ks = 0; ks < 2; ks++) {
        size_t off = ((size_t)bh * SEQ + qrow0 + l15) * DHEAD + ks * 32 + quad * 8;
        aqh[ks] = *(const bf16x8*)&Qh_hi[off];
        aql[ks] = *(const bf16x8*)&Qh_lo[off];
    }

    // per-thread staging coords (identical coverage to round-2 stage loop)
    const int sr = tid >> 3;          // 0..31
    const int sc = (tid & 7) * 8;     // 0..56
    bf16x8 skh[2], skl[2], sv[2];     // in-flight tile registers

    #pragma unroll
    for (int i = 0; i < 2; i++) {     // prologue: tile 0 -> regs
        int r = sr + i * 32;
        size_t gk = (size_t)r * DHEAD + sc;
        size_t gv = (size_t)r * SEQ + sc;
        skh[i] = *(const bf16x8*)&Kh_hi_b[gk];
        skl[i] = *(const bf16x8*)&Kh_lo_b[gk];
        sv[i]  = *(const bf16x8*)&Vh_b[gv];
    }

    const f32x4 zf = {0.f, 0.f, 0.f, 0.f};
    f32x4 cacc[4];
    #pragma unroll
    for (int fj = 0; fj < 4; fj++) cacc[fj] = zf;
    float lrun[4] = {};

    constexpr int NT = SEQ / 64;
    for (int kt = 0; kt < NT; kt++) {
        const int k0 = kt * 64;

        // publish staged tile to LDS
        #pragma unroll
        for (int i = 0; i < 2; i++) {
            int r = sr + i * 32;
            *(bf16x8*)&Ks_hi[r * 72 + sc] = skh[i];
            *(bf16x8*)&Ks_lo[r * 72 + sc] = skl[i];
            *(bf16x8*)&Vs[r * 72 + sc]    = sv[i];
        }
        __syncthreads();

        // issue NEXT tile's loads now; consumed after the closing barrier
        if (kt + 1 < NT) {
            const int kn = k0 + 64;
            #pragma unroll
            for (int i = 0; i < 2; i++) {
                int r = sr + i * 32;
                size_t gk = (size_t)(kn + r) * DHEAD + sc;
                size_t gv = (size_t)r * SEQ + kn + sc;
                skh[i] = *(const bf16x8*)&Kh_hi_b[gk];
                skl[i] = *(const bf16x8*)&Kh_lo_b[gk];
                sv[i]  = *(const bf16x8*)&Vh_b[gv];
            }
        }

        // QK^T (q pre-scaled by 1/8)
        f32x4 sacc[4];
        #pragma unroll
        for (int fj = 0; fj < 4; fj++) sacc[fj] = zf;

        #pragma unroll
        for (int ks = 0; ks < 2; ks++) {
            bf16x8 kh[4], kl[4];
            #pragma unroll
            for (int fj = 0; fj < 4; fj++) {
                int off = (fj * 16 + l15) * 72 + ks * 32 + quad * 8;
                kh[fj] = *(const bf16x8*)&Ks_hi[off];
                kl[fj] = *(const bf16x8*)&Ks_lo[off];
            }
            #pragma unroll
            for (int fj = 0; fj < 4; fj++) {
                sacc[fj] = MFMA_BF16(aqh[ks], kh[fj], sacc[fj]);
                sacc[fj] = MFMA_BF16(aqh[ks], kl[fj], sacc[fj]);
                sacc[fj] = MFMA_BF16(aql[ks], kh[fj], sacc[fj]);
            }
        }

        // p~ = exp(s + bias); bf16 p~ to this wave's Ps stripe, row sums
        float tsum[4] = {};
        #pragma unroll
        for (int fj = 0; fj < 4; fj++) {
            float bias = bias_s[k0 + fj * 16 + l15];
            #pragma unroll
            for (int r = 0; r < 4; r++) {
                float s = sacc[fj][r] + bias;
                s = fminf(s, 80.0f);
                float p = __expf(s);
                Ps[(wid * 16 + quad * 4 + r) * 72 + fj * 16 + l15] = (__bf16)p;
                tsum[r] += p;
            }
        }
        #pragma unroll
        for (int r = 0; r < 4; r++) {
            float t = tsum[r];
            t += __shfl_xor(t, 1);
            t += __shfl_xor(t, 2);
            t += __shfl_xor(t, 4);
            t += __shfl_xor(t, 8);
            lrun[r] += t;
        }

        // PV (plain bf16): A = this wave's Ps rows (wave-private stripe,
        // same-wave DS ordering), B = Vs (V^T)
        #pragma unroll
        for (int ks = 0; ks < 2; ks++) {
            bf16x8 ph = *(const bf16x8*)&Ps[(wid * 16 + l15) * 72 + ks * 32 + quad * 8];
            #pragma unroll
            for (int fj = 0; fj < 4; fj++) {
                bf16x8 vh = *(const bf16x8*)&Vs[(fj * 16 + l15) * 72 + ks * 32 + quad * 8];
                cacc[fj] = MFMA_BF16(ph, vh, cacc[fj]);
            }
        }
        __syncthreads();
    }

    #pragma unroll
    for (int r = 0; r < 4; r++) {
        int rl_ = quad * 4 + r;
        int row = qrow0 + rl_;
        float lv = lrun[r];
        if (l15 == 0)
            lsum[(size_t)bh * SEQ + row] = lv;
        float inv = 1.0f / lv;
        #pragma unroll
        for (int fj = 0; fj < 4; fj++)
            ctx[((size_t)b * SEQ + row) * DMODEL + h * DHEAD + fj * 16 + l15] =
                cacc[fj][r] * inv;
    }
}

// ---------------------------------------------------------------------------
// K2b: weights writer.  Recomputes QK^T+exp (bit-identical 3-MFMA split),
// scales by 1/lsum, writes full normalized rows.  Round-2 staged structure
// + T14 async-STAGE split on the K tiles.
// ---------------------------------------------------------------------------
__global__ __launch_bounds__(256) void attn_weights_kernel(
    const __bf16* __restrict__ Qh_hi, const __bf16* __restrict__ Qh_lo,
    const __bf16* __restrict__ Kh_hi, const __bf16* __restrict__ Kh_lo,
    const float* __restrict__ mask,
    const float* __restrict__ lsum,
    float* __restrict__ wout)      // [B,H,S,S]
{
    const int qt = blockIdx.x;
    const int h  = blockIdx.y;
    const int b  = blockIdx.z;
    const int bh = b * HEADS + h;

    const int tid  = threadIdx.x;
    const int wid  = tid >> 6;
    const int lane = tid & 63;
    const int quad = lane >> 4;
    const int l15  = lane & 15;
    const int qrow0 = qt * 64 + wid * 16;

    __shared__ __bf16 Ks_hi[64 * 72];
    __shared__ __bf16 Ks_lo[64 * 72];
    __shared__ float bias_s[SEQ];

    for (int i = tid; i < SEQ; i += 256)
        bias_s[i] = (mask[b * SEQ + i] != 0.0f) ? -1e30f : 0.0f;

    const __bf16* Kh_hi_b = Kh_hi + (size_t)bh * SEQ * DHEAD;
    const __bf16* Kh_lo_b = Kh_lo + (size_t)bh * SEQ * DHEAD;

    bf16x8 aqh[2], aql[2];
    #pragma unroll
    for (int ks = 0; ks < 2; ks++) {
        size_t off = ((size_t)bh * SEQ + qrow0 + l15) * DHEAD + ks * 32 + quad * 8;
        aqh[ks] = *(const bf16x8*)&Qh_hi[off];
        aql[ks] = *(const bf16x8*)&Qh_lo[off];
    }

    float inv[4];
    #pragma unroll
    for (int r = 0; r < 4; r++)
        inv[r] = 1.0f / lsum[(size_t)bh * SEQ + qrow0 + quad * 4 + r];

    const int sr = tid >> 3;
    const int sc = (tid & 7) * 8;
    bf16x8 skh[2], skl[2];

    #pragma unroll
    for (int i = 0; i < 2; i++) {     // prologue: tile 0 -> regs
        int r = sr + i * 32;
        size_t gk = (size_t)r * DHEAD + sc;
        skh[i] = *(const bf16x8*)&Kh_hi_b[gk];
        skl[i] = *(const bf16x8*)&Kh_lo_b[gk];
    }

    const f32x4 zf = {0.f, 0.f, 0.f, 0.f};

    constexpr int NT = SEQ / 64;
    for (int kt = 0; kt < NT; kt++) {
        const int k0 = kt * 64;

        #pragma unroll
        for (int i = 0; i < 2; i++) {
            int r = sr + i * 32;
            *(bf16x8*)&Ks_hi[r * 72 + sc] = skh[i];
            *(bf16x8*)&Ks_lo[r * 72 + sc] = skl[i];
        }
        __syncthreads();

        if (kt + 1 < NT) {
            const int kn = k0 + 64;
            #pragma unroll
            for (int i = 0; i < 2; i++) {
                int r = sr + i * 32;
                size_t gk = (size_t)(kn + r) * DHEAD + sc;
                skh[i] = *(const bf16x8*)&Kh_hi_b[gk];
                skl[i] = *(const bf16x8*)&Kh_lo_b[gk];
            }
        }

        f32x4 sacc[4];
        #pragma unroll
        for (int fj = 0; fj < 4; fj++) sacc[fj] = zf;

        #pragma unroll
        for (int ks = 0; ks < 2; ks++) {
            bf16x8 kh[4], kl[4];
            #pragma unroll
            for (int fj = 0; fj < 4; fj++) {
                int off = (fj * 16 + l15) * 72 + ks * 32 + quad * 8;
                kh[fj] = *(const bf16x8*)&Ks_hi[off];
                kl[fj] = *(const bf16x8*)&Ks_lo[off];
            }
            #pragma unroll
            for (int fj = 0; fj < 4; fj++) {
                sacc[fj] = MFMA_BF16(aqh[ks], kh[fj], sacc[fj]);
                sacc[fj] = MFMA_BF16(aqh[ks], kl[fj], sacc[fj]);
                sacc[fj] = MFMA_BF16(aql[ks], kh[fj], sacc[fj]);
            }
        }

        #pragma unroll
        for (int fj = 0; fj < 4; fj++) {
            float bias = bias_s[k0 + fj * 16 + l15];
            #pragma unroll
            for (int r = 0; r < 4; r++) {
                float s = sacc[fj][r] + bias;
                s = fminf(s, 80.0f);
                float p = __expf(s);
                int row = qrow0 + quad * 4 + r;
                wout[((size_t)bh * SEQ + row) * SEQ + k0 + fj * 16 + l15] = p * inv[r];
            }
        }
        __syncthreads();
    }
}

// ---------------------------------------------------------------------------
// K4: output projection: out = ctx @ Wo.T + bo  (f32 out)
// ---------------------------------------------------------------------------
__global__ __launch_bounds__(256) void out_proj_kernel(
    const float* __restrict__ X, const float* __restrict__ W, const float* __restrict__ bias,
    float* __restrict__ out)
{
    __shared__ __bf16 As_hi[128 * 40];
    __shared__ __bf16 As_lo[128 * 40];
    __shared__ __bf16 Bs_hi[128 * 40];
    __shared__ __bf16 Bs_lo[128 * 40];

    const int tid  = threadIdx.x;
    const int wid  = tid >> 6;
    const int lane = tid & 63;
    const int quad = lane >> 4;
    const int l15  = lane & 15;
    const int wm = (wid >> 1) * 64;
    const int wn = (wid & 1) * 64;
    const int mbase = blockIdx.x * 128;
    const int nbase = blockIdx.y * 128;

    const f32x4 zf = {0.f, 0.f, 0.f, 0.f};
    f32x4 acc[4][4];
    #pragma unroll
    for (int i = 0; i < 4; i++)
        #pragma unroll
        for (int j = 0; j < 4; j++) acc[i][j] = zf;

    for (int k0 = 0; k0 < DMODEL; k0 += 32) {
        #pragma unroll
        for (int i = 0; i < 4; i++) {
            int idx = i * 256 + tid;
            int r = idx >> 3;
            int c = (idx & 7) * 4;
            float4 a4 = *(const float4*)&X[(size_t)(mbase + r) * DMODEL + k0 + c];
            float4 b4 = *(const float4*)&W[(size_t)(nbase + r) * DMODEL + k0 + c];
            float af[4] = {a4.x, a4.y, a4.z, a4.w};
            float bf[4] = {b4.x, b4.y, b4.z, b4.w};
            bf16x4 ah4, al4, bh4, bl4;
            #pragma unroll
            for (int j = 0; j < 4; j++) {
                __bf16 hi, lo;
                split_bf16(af[j], hi, lo); ah4[j] = hi; al4[j] = lo;
                split_bf16(bf[j], hi, lo); bh4[j] = hi; bl4[j] = lo;
            }
            *(bf16x4*)&As_hi[r * 40 + c] = ah4;
            *(bf16x4*)&As_lo[r * 40 + c] = al4;
            *(bf16x4*)&Bs_hi[r * 40 + c] = bh4;
            *(bf16x4*)&Bs_lo[r * 40 + c] = bl4;
        }
        __syncthreads();

        bf16x8 ah[4], al[4], bh[4], bl[4];
        #pragma unroll
        for (int f = 0; f < 4; f++) {
            int ra = (wm + f * 16 + l15) * 40 + quad * 8;
            ah[f] = *(const bf16x8*)&As_hi[ra];
            al[f] = *(const bf16x8*)&As_lo[ra];
            int rb = (wn + f * 16 + l15) * 40 + quad * 8;
            bh[f] = *(const bf16x8*)&Bs_hi[rb];
            bl[f] = *(const bf16x8*)&Bs_lo[rb];
        }
        #pragma unroll
        for (int fi = 0; fi < 4; fi++)
            #pragma unroll
            for (int fj = 0; fj < 4; fj++) {
                acc[fi][fj] = MFMA_BF16(ah[fi], bh[fj], acc[fi][fj]);
                acc[fi][fj] = MFMA_BF16(ah[fi], bl[fj], acc[fi][fj]);
                acc[fi][fj] = MFMA_BF16(al[fi], bh[fj], acc[fi][fj]);
            }
        __syncthreads();
    }

    float bvals[4];
    #pragma unroll
    for (int fj = 0; fj < 4; fj++)
        bvals[fj] = bias[nbase + wn + fj * 16 + l15];

    #pragma unroll
    for (int fi = 0; fi < 4; fi++)
        #pragma unroll
        for (int fj = 0; fj < 4; fj++)
            #pragma unroll
            for (int r = 0; r < 4; r++) {
                int m = mbase + wm + fi * 16 + quad * 4 + r;
                int n = nbase + wn + fj * 16 + l15;
                out[(size_t)m * DMODEL + n] = acc[fi][fj][r] + bvals[fj];
            }
}

// ---------------------------------------------------------------------------
extern "C" void kernel_launch(void* const* d_in, const int* in_sizes, int n_in,
                              void* d_out, int out_size, void* d_ws, size_t ws_size,
                              hipStream_t stream) {
    (void)in_sizes; (void)n_in; (void)out_size; (void)ws_size;

    const float* q    = (const float*)d_in[0];
    const float* k    = (const float*)d_in[1];
    const float* v    = (const float*)d_in[2];
    const float* mask = (const float*)d_in[3];
    const float* Wq   = (const float*)d_in[4];
    const float* bq   = (const float*)d_in[5];
    const float* Wk   = (const float*)d_in[6];
    const float* bk   = (const float*)d_in[7];
    const float* Wv   = (const float*)d_in[8];
    const float* bv   = (const float*)d_in[9];
    const float* Wo   = (const float*)d_in[10];
    const float* bo   = (const float*)d_in[11];

    float* out  = (float*)d_out;
    float* wout = out + (size_t)OUT_ELEMS;     // weights region of d_out

    // workspace layout (~44.2 MB):
    __bf16* wsb = (__bf16*)d_ws;
    __bf16* Qh_hi = wsb;
    __bf16* Qh_lo = wsb + 1 * (size_t)HEAD_ELEMS;
    __bf16* Kh_hi = wsb + 2 * (size_t)HEAD_ELEMS;
    __bf16* Kh_lo = wsb + 3 * (size_t)HEAD_ELEMS;
    __bf16* Vh    = wsb + 4 * (size_t)HEAD_ELEMS;
    float*  ctx   = (float*)(wsb + 5 * (size_t)HEAD_ELEMS);
    float*  lsum  = ctx + (size_t)OUT_ELEMS;

    qkv_proj_kernel<<<dim3(32, 6, 3), 256, 0, stream>>>(
        q, k, v, Wq, bq, Wk, bk, Wv, bv,
        Qh_hi, Qh_lo, Kh_hi, Kh_lo, Vh);

    attn_ctx_kernel<<<dim3(32, 12, 2), 256, 0, stream>>>(
        Qh_hi, Qh_lo, Kh_hi, Kh_lo, Vh, mask, ctx, lsum);

    attn_weights_kernel<<<dim3(32, 12, 2), 256, 0, stream>>>(
        Qh_hi, Qh_lo, Kh_hi, Kh_lo, mask, lsum, wout);

    out_proj_kernel<<<dim3(32, 6, 1), 256, 0, stream>>>(ctx, Wo, bo, out);
}

// Round 5
// 698.919 us; speedup vs baseline: 1.4017x; 1.0348x over previous
//
#include <hip/hip_runtime.h>

typedef __bf16 bf16x8 __attribute__((ext_vector_type(8)));
typedef __bf16 bf16x4 __attribute__((ext_vector_type(4)));
typedef float  f32x4  __attribute__((ext_vector_type(4)));

#define MFMA_BF16(a, b, c) __builtin_amdgcn_mfma_f32_16x16x32_bf16((a), (b), (c), 0, 0, 0)

static constexpr int BATCH  = 2;
static constexpr int HEADS  = 12;
static constexpr int SEQ    = 2048;
static constexpr int DHEAD  = 64;
static constexpr int DMODEL = 768;
static constexpr int M_ROWS = BATCH * SEQ;                     // 4096
static constexpr int OUT_ELEMS  = M_ROWS * DMODEL;             // 3145728
static constexpr int HEAD_ELEMS = BATCH * HEADS * SEQ * DHEAD; // 3145728

__device__ __forceinline__ void split_bf16(float x, __bf16 &hi, __bf16 &lo) {
    __bf16 h = (__bf16)x;
    hi = h;
    lo = (__bf16)(x - (float)h);
}

// ---------------------------------------------------------------------------
// K1: fused QKV projection.  out = X @ W.T + b, split to bf16 hi/lo.
//  z=0: Q (scaled 1/8), layout [b,h,s,d], hi+lo
//  z=1: K full rows      [b,h,s,d], hi+lo
//  z=2: V transposed     [b,h,d,s], hi only
// ---------------------------------------------------------------------------
__global__ __launch_bounds__(256) void qkv_proj_kernel(
    const float* __restrict__ qin, const float* __restrict__ kin, const float* __restrict__ vin,
    const float* __restrict__ Wq, const float* __restrict__ bq,
    const float* __restrict__ Wk, const float* __restrict__ bk,
    const float* __restrict__ Wv, const float* __restrict__ bv,
    __bf16* __restrict__ Qh_hi, __bf16* __restrict__ Qh_lo,
    __bf16* __restrict__ Kh_hi, __bf16* __restrict__ Kh_lo,
    __bf16* __restrict__ Vh)
{
    const int z = blockIdx.z;
    const float* X; const float* W; const float* bias;
    float scale = 1.0f;
    if (z == 0)      { X = qin; W = Wq; bias = bq; scale = 0.125f; }
    else if (z == 1) { X = kin; W = Wk; bias = bk; }
    else             { X = vin; W = Wv; bias = bv; }

    __shared__ __bf16 As_hi[128 * 40];
    __shared__ __bf16 As_lo[128 * 40];
    __shared__ __bf16 Bs_hi[128 * 40];
    __shared__ __bf16 Bs_lo[128 * 40];

    const int tid  = threadIdx.x;
    const int wid  = tid >> 6;
    const int lane = tid & 63;
    const int quad = lane >> 4;
    const int l15  = lane & 15;
    const int wm = (wid >> 1) * 64;
    const int wn = (wid & 1) * 64;
    const int mbase = blockIdx.x * 128;
    const int nbase = blockIdx.y * 128;

    const f32x4 zf = {0.f, 0.f, 0.f, 0.f};
    f32x4 acc[4][4];
    #pragma unroll
    for (int i = 0; i < 4; i++)
        #pragma unroll
        for (int j = 0; j < 4; j++) acc[i][j] = zf;

    for (int k0 = 0; k0 < DMODEL; k0 += 32) {
        #pragma unroll
        for (int i = 0; i < 4; i++) {
            int idx = i * 256 + tid;
            int r = idx >> 3;
            int c = (idx & 7) * 4;
            float4 a4 = *(const float4*)&X[(size_t)(mbase + r) * DMODEL + k0 + c];
            float4 b4 = *(const float4*)&W[(size_t)(nbase + r) * DMODEL + k0 + c];
            float af[4] = {a4.x, a4.y, a4.z, a4.w};
            float bf[4] = {b4.x, b4.y, b4.z, b4.w};
            bf16x4 ah4, al4, bh4, bl4;
            #pragma unroll
            for (int j = 0; j < 4; j++) {
                __bf16 hi, lo;
                split_bf16(af[j], hi, lo); ah4[j] = hi; al4[j] = lo;
                split_bf16(bf[j], hi, lo); bh4[j] = hi; bl4[j] = lo;
            }
            *(bf16x4*)&As_hi[r * 40 + c] = ah4;
            *(bf16x4*)&As_lo[r * 40 + c] = al4;
            *(bf16x4*)&Bs_hi[r * 40 + c] = bh4;
            *(bf16x4*)&Bs_lo[r * 40 + c] = bl4;
        }
        __syncthreads();

        bf16x8 ah[4], al[4], bh[4], bl[4];
        #pragma unroll
        for (int f = 0; f < 4; f++) {
            int ra = (wm + f * 16 + l15) * 40 + quad * 8;
            ah[f] = *(const bf16x8*)&As_hi[ra];
            al[f] = *(const bf16x8*)&As_lo[ra];
            int rb = (wn + f * 16 + l15) * 40 + quad * 8;
            bh[f] = *(const bf16x8*)&Bs_hi[rb];
            bl[f] = *(const bf16x8*)&Bs_lo[rb];
        }
        #pragma unroll
        for (int fi = 0; fi < 4; fi++)
            #pragma unroll
            for (int fj = 0; fj < 4; fj++) {
                acc[fi][fj] = MFMA_BF16(ah[fi], bh[fj], acc[fi][fj]);
                acc[fi][fj] = MFMA_BF16(ah[fi], bl[fj], acc[fi][fj]);
                acc[fi][fj] = MFMA_BF16(al[fi], bh[fj], acc[fi][fj]);
            }
        __syncthreads();
    }

    float bvals[4];
    #pragma unroll
    for (int fj = 0; fj < 4; fj++)
        bvals[fj] = bias[nbase + wn + fj * 16 + l15];

    #pragma unroll
    for (int fi = 0; fi < 4; fi++)
        #pragma unroll
        for (int fj = 0; fj < 4; fj++)
            #pragma unroll
            for (int r = 0; r < 4; r++) {
                int m = mbase + wm + fi * 16 + quad * 4 + r;
                int n = nbase + wn + fj * 16 + l15;
                float val = (acc[fi][fj][r] + bvals[fj]) * scale;
                __bf16 hi, lo;
                split_bf16(val, hi, lo);
                int bb = m >> 11;
                int s  = m & (SEQ - 1);
                int hh = n >> 6;
                int d  = n & 63;
                int bh_ = bb * HEADS + hh;
                if (z == 0) {
                    size_t idx = ((size_t)bh_ * SEQ + s) * DHEAD + d;
                    Qh_hi[idx] = hi; Qh_lo[idx] = lo;
                } else if (z == 1) {
                    size_t idx = ((size_t)bh_ * SEQ + s) * DHEAD + d;
                    Kh_hi[idx] = hi; Kh_lo[idx] = lo;
                } else {
                    size_t idx = ((size_t)bh_ * DHEAD + d) * SEQ + s;
                    Vh[idx] = hi;
                }
            }
}

// ---------------------------------------------------------------------------
// K2: FUSED attention.  Phase 1 (ctx): per 64-key tile QK -> exp -> row-sums
// -> PV, accumulating ctx and per-row sums in registers.  Phase 2 (weights):
// inv = 1/lrun (straight from registers -- no lsum round-trip), recompute
// QK^T+exp bit-identically and write normalized weight rows.  Q fragments
// and bias_s survive in registers/LDS across phases; Ks staging LDS reused.
// ---------------------------------------------------------------------------
__global__ __launch_bounds__(256) void attn_fused_kernel(
    const __bf16* __restrict__ Qh_hi, const __bf16* __restrict__ Qh_lo,
    const __bf16* __restrict__ Kh_hi, const __bf16* __restrict__ Kh_lo,
    const __bf16* __restrict__ Vh,
    const float* __restrict__ mask,
    float* __restrict__ ctx,       // [B,S,DMODEL]
    float* __restrict__ wout)      // [B,H,S,S]
{
    const int qt = blockIdx.x;
    const int h  = blockIdx.y;
    const int b  = blockIdx.z;
    const int bh = b * HEADS + h;

    const int tid  = threadIdx.x;
    const int wid  = tid >> 6;
    const int lane = tid & 63;
    const int quad = lane >> 4;
    const int l15  = lane & 15;
    const int qrow0 = qt * 64 + wid * 16;

    __shared__ __bf16 Ks_hi[64 * 72];
    __shared__ __bf16 Ks_lo[64 * 72];
    __shared__ __bf16 Vs[64 * 72];
    __shared__ __bf16 Ps[64 * 72];
    __shared__ float bias_s[SEQ];

    for (int i = tid; i < SEQ; i += 256)
        bias_s[i] = (mask[b * SEQ + i] != 0.0f) ? -1e30f : 0.0f;

    const __bf16* Kh_hi_b = Kh_hi + (size_t)bh * SEQ * DHEAD;
    const __bf16* Kh_lo_b = Kh_lo + (size_t)bh * SEQ * DHEAD;
    const __bf16* Vh_b    = Vh    + (size_t)bh * DHEAD * SEQ;

    // Q fragments for this wave's 16 rows (hi/lo, 64-d split in two 32-chunks)
    bf16x8 aqh[2], aql[2];
    #pragma unroll
    for (int ks = 0; ks < 2; ks++) {
        size_t off = ((size_t)bh * SEQ + qrow0 + l15) * DHEAD + ks * 32 + quad * 8;
        aqh[ks] = *(const bf16x8*)&Qh_hi[off];
        aql[ks] = *(const bf16x8*)&Qh_lo[off];
    }

    // per-thread staging coords
    const int sr = tid >> 3;          // 0..31
    const int sc = (tid & 7) * 8;     // 0..56
    bf16x8 skh[2], skl[2], sv[2];

    #pragma unroll
    for (int i = 0; i < 2; i++) {     // prologue: tile 0 -> regs
        int r = sr + i * 32;
        size_t gk = (size_t)r * DHEAD + sc;
        size_t gv = (size_t)r * SEQ + sc;
        skh[i] = *(const bf16x8*)&Kh_hi_b[gk];
        skl[i] = *(const bf16x8*)&Kh_lo_b[gk];
        sv[i]  = *(const bf16x8*)&Vh_b[gv];
    }

    const f32x4 zf = {0.f, 0.f, 0.f, 0.f};
    f32x4 cacc[4];
    #pragma unroll
    for (int fj = 0; fj < 4; fj++) cacc[fj] = zf;
    float lrun[4] = {};

    constexpr int NT = SEQ / 64;

    // ---------------- Phase 1: ctx + row sums ----------------
    for (int kt = 0; kt < NT; kt++) {
        const int k0 = kt * 64;

        #pragma unroll
        for (int i = 0; i < 2; i++) {
            int r = sr + i * 32;
            *(bf16x8*)&Ks_hi[r * 72 + sc] = skh[i];
            *(bf16x8*)&Ks_lo[r * 72 + sc] = skl[i];
            *(bf16x8*)&Vs[r * 72 + sc]    = sv[i];
        }
        __syncthreads();

        if (kt + 1 < NT) {
            const int kn = k0 + 64;
            #pragma unroll
            for (int i = 0; i < 2; i++) {
                int r = sr + i * 32;
                size_t gk = (size_t)(kn + r) * DHEAD + sc;
                size_t gv = (size_t)r * SEQ + kn + sc;
                skh[i] = *(const bf16x8*)&Kh_hi_b[gk];
                skl[i] = *(const bf16x8*)&Kh_lo_b[gk];
                sv[i]  = *(const bf16x8*)&Vh_b[gv];
            }
        }

        // QK^T (q pre-scaled by 1/8)
        f32x4 sacc[4];
        #pragma unroll
        for (int fj = 0; fj < 4; fj++) sacc[fj] = zf;

        #pragma unroll
        for (int ks = 0; ks < 2; ks++) {
            bf16x8 kh[4], kl[4];
            #pragma unroll
            for (int fj = 0; fj < 4; fj++) {
                int off = (fj * 16 + l15) * 72 + ks * 32 + quad * 8;
                kh[fj] = *(const bf16x8*)&Ks_hi[off];
                kl[fj] = *(const bf16x8*)&Ks_lo[off];
            }
            #pragma unroll
            for (int fj = 0; fj < 4; fj++) {
                sacc[fj] = MFMA_BF16(aqh[ks], kh[fj], sacc[fj]);
                sacc[fj] = MFMA_BF16(aqh[ks], kl[fj], sacc[fj]);
                sacc[fj] = MFMA_BF16(aql[ks], kh[fj], sacc[fj]);
            }
        }

        // p~ = exp(s + bias); bf16 p~ to this wave's Ps stripe, row sums
        float tsum[4] = {};
        #pragma unroll
        for (int fj = 0; fj < 4; fj++) {
            float bias = bias_s[k0 + fj * 16 + l15];
            #pragma unroll
            for (int r = 0; r < 4; r++) {
                float s = sacc[fj][r] + bias;
                s = fminf(s, 80.0f);
                float p = __expf(s);
                Ps[(wid * 16 + quad * 4 + r) * 72 + fj * 16 + l15] = (__bf16)p;
                tsum[r] += p;
            }
        }
        #pragma unroll
        for (int r = 0; r < 4; r++) {
            float t = tsum[r];
            t += __shfl_xor(t, 1);
            t += __shfl_xor(t, 2);
            t += __shfl_xor(t, 4);
            t += __shfl_xor(t, 8);
            lrun[r] += t;
        }

        // PV (plain bf16): A = this wave's Ps rows, B = Vs (V^T)
        #pragma unroll
        for (int ks = 0; ks < 2; ks++) {
            bf16x8 ph = *(const bf16x8*)&Ps[(wid * 16 + l15) * 72 + ks * 32 + quad * 8];
            #pragma unroll
            for (int fj = 0; fj < 4; fj++) {
                bf16x8 vh = *(const bf16x8*)&Vs[(fj * 16 + l15) * 72 + ks * 32 + quad * 8];
                cacc[fj] = MFMA_BF16(ph, vh, cacc[fj]);
            }
        }
        __syncthreads();
    }

    // inv from registers (same sums the weights must be normalized by)
    float inv[4];
    #pragma unroll
    for (int r = 0; r < 4; r++) {
        int rl_ = quad * 4 + r;
        int row = qrow0 + rl_;
        float lv = lrun[r];
        inv[r] = 1.0f / lv;
        #pragma unroll
        for (int fj = 0; fj < 4; fj++)
            ctx[((size_t)b * SEQ + row) * DMODEL + h * DHEAD + fj * 16 + l15] =
                cacc[fj][r] * inv[r];
    }

    // ---------------- Phase 2: normalized weights ----------------
    // reload tile 0 (K only); Ks LDS is free past the final phase-1 barrier
    #pragma unroll
    for (int i = 0; i < 2; i++) {
        int r = sr + i * 32;
        size_t gk = (size_t)r * DHEAD + sc;
        skh[i] = *(const bf16x8*)&Kh_hi_b[gk];
        skl[i] = *(const bf16x8*)&Kh_lo_b[gk];
    }

    for (int kt = 0; kt < NT; kt++) {
        const int k0 = kt * 64;

        #pragma unroll
        for (int i = 0; i < 2; i++) {
            int r = sr + i * 32;
            *(bf16x8*)&Ks_hi[r * 72 + sc] = skh[i];
            *(bf16x8*)&Ks_lo[r * 72 + sc] = skl[i];
        }
        __syncthreads();

        if (kt + 1 < NT) {
            const int kn = k0 + 64;
            #pragma unroll
            for (int i = 0; i < 2; i++) {
                int r = sr + i * 32;
                size_t gk = (size_t)(kn + r) * DHEAD + sc;
                skh[i] = *(const bf16x8*)&Kh_hi_b[gk];
                skl[i] = *(const bf16x8*)&Kh_lo_b[gk];
            }
        }

        f32x4 sacc[4];
        #pragma unroll
        for (int fj = 0; fj < 4; fj++) sacc[fj] = zf;

        #pragma unroll
        for (int ks = 0; ks < 2; ks++) {
            bf16x8 kh[4], kl[4];
            #pragma unroll
            for (int fj = 0; fj < 4; fj++) {
                int off = (fj * 16 + l15) * 72 + ks * 32 + quad * 8;
                kh[fj] = *(const bf16x8*)&Ks_hi[off];
                kl[fj] = *(const bf16x8*)&Ks_lo[off];
            }
            #pragma unroll
            for (int fj = 0; fj < 4; fj++) {
                sacc[fj] = MFMA_BF16(aqh[ks], kh[fj], sacc[fj]);
                sacc[fj] = MFMA_BF16(aqh[ks], kl[fj], sacc[fj]);
                sacc[fj] = MFMA_BF16(aql[ks], kh[fj], sacc[fj]);
            }
        }

        #pragma unroll
        for (int fj = 0; fj < 4; fj++) {
            float bias = bias_s[k0 + fj * 16 + l15];
            #pragma unroll
            for (int r = 0; r < 4; r++) {
                float s = sacc[fj][r] + bias;
                s = fminf(s, 80.0f);
                float p = __expf(s);
                int row = qrow0 + quad * 4 + r;
                wout[((size_t)bh * SEQ + row) * SEQ + k0 + fj * 16 + l15] = p * inv[r];
            }
        }
        __syncthreads();
    }
}

// ---------------------------------------------------------------------------
// K4: output projection: out = ctx @ Wo.T + bo  (f32 out)
// ---------------------------------------------------------------------------
__global__ __launch_bounds__(256) void out_proj_kernel(
    const float* __restrict__ X, const float* __restrict__ W, const float* __restrict__ bias,
    float* __restrict__ out)
{
    __shared__ __bf16 As_hi[128 * 40];
    __shared__ __bf16 As_lo[128 * 40];
    __shared__ __bf16 Bs_hi[128 * 40];
    __shared__ __bf16 Bs_lo[128 * 40];

    const int tid  = threadIdx.x;
    const int wid  = tid >> 6;
    const int lane = tid & 63;
    const int quad = lane >> 4;
    const int l15  = lane & 15;
    const int wm = (wid >> 1) * 64;
    const int wn = (wid & 1) * 64;
    const int mbase = blockIdx.x * 128;
    const int nbase = blockIdx.y * 128;

    const f32x4 zf = {0.f, 0.f, 0.f, 0.f};
    f32x4 acc[4][4];
    #pragma unroll
    for (int i = 0; i < 4; i++)
        #pragma unroll
        for (int j = 0; j < 4; j++) acc[i][j] = zf;

    for (int k0 = 0; k0 < DMODEL; k0 += 32) {
        #pragma unroll
        for (int i = 0; i < 4; i++) {
            int idx = i * 256 + tid;
            int r = idx >> 3;
            int c = (idx & 7) * 4;
            float4 a4 = *(const float4*)&X[(size_t)(mbase + r) * DMODEL + k0 + c];
            float4 b4 = *(const float4*)&W[(size_t)(nbase + r) * DMODEL + k0 + c];
            float af[4] = {a4.x, a4.y, a4.z, a4.w};
            float bf[4] = {b4.x, b4.y, b4.z, b4.w};
            bf16x4 ah4, al4, bh4, bl4;
            #pragma unroll
            for (int j = 0; j < 4; j++) {
                __bf16 hi, lo;
                split_bf16(af[j], hi, lo); ah4[j] = hi; al4[j] = lo;
                split_bf16(bf[j], hi, lo); bh4[j] = hi; bl4[j] = lo;
            }
            *(bf16x4*)&As_hi[r * 40 + c] = ah4;
            *(bf16x4*)&As_lo[r * 40 + c] = al4;
            *(bf16x4*)&Bs_hi[r * 40 + c] = bh4;
            *(bf16x4*)&Bs_lo[r * 40 + c] = bl4;
        }
        __syncthreads();

        bf16x8 ah[4], al[4], bh[4], bl[4];
        #pragma unroll
        for (int f = 0; f < 4; f++) {
            int ra = (wm + f * 16 + l15) * 40 + quad * 8;
            ah[f] = *(const bf16x8*)&As_hi[ra];
            al[f] = *(const bf16x8*)&As_lo[ra];
            int rb = (wn + f * 16 + l15) * 40 + quad * 8;
            bh[f] = *(const bf16x8*)&Bs_hi[rb];
            bl[f] = *(const bf16x8*)&Bs_lo[rb];
        }
        #pragma unroll
        for (int fi = 0; fi < 4; fi++)
            #pragma unroll
            for (int fj = 0; fj < 4; fj++) {
                acc[fi][fj] = MFMA_BF16(ah[fi], bh[fj], acc[fi][fj]);
                acc[fi][fj] = MFMA_BF16(ah[fi], bl[fj], acc[fi][fj]);
                acc[fi][fj] = MFMA_BF16(al[fi], bh[fj], acc[fi][fj]);
            }
        __syncthreads();
    }

    float bvals[4];
    #pragma unroll
    for (int fj = 0; fj < 4; fj++)
        bvals[fj] = bias[nbase + wn + fj * 16 + l15];

    #pragma unroll
    for (int fi = 0; fi < 4; fi++)
        #pragma unroll
        for (int fj = 0; fj < 4; fj++)
            #pragma unroll
            for (int r = 0; r < 4; r++) {
                int m = mbase + wm + fi * 16 + quad * 4 + r;
                int n = nbase + wn + fj * 16 + l15;
                out[(size_t)m * DMODEL + n] = acc[fi][fj][r] + bvals[fj];
            }
}

// ---------------------------------------------------------------------------
extern "C" void kernel_launch(void* const* d_in, const int* in_sizes, int n_in,
                              void* d_out, int out_size, void* d_ws, size_t ws_size,
                              hipStream_t stream) {
    (void)in_sizes; (void)n_in; (void)out_size; (void)ws_size;

    const float* q    = (const float*)d_in[0];
    const float* k    = (const float*)d_in[1];
    const float* v    = (const float*)d_in[2];
    const float* mask = (const float*)d_in[3];
    const float* Wq   = (const float*)d_in[4];
    const float* bq   = (const float*)d_in[5];
    const float* Wk   = (const float*)d_in[6];
    const float* bk   = (const float*)d_in[7];
    const float* Wv   = (const float*)d_in[8];
    const float* bv   = (const float*)d_in[9];
    const float* Wo   = (const float*)d_in[10];
    const float* bo   = (const float*)d_in[11];

    float* out  = (float*)d_out;
    float* wout = out + (size_t)OUT_ELEMS;     // weights region of d_out

    // workspace layout (~37 MB):
    __bf16* wsb = (__bf16*)d_ws;
    __bf16* Qh_hi = wsb;
    __bf16* Qh_lo = wsb + 1 * (size_t)HEAD_ELEMS;
    __bf16* Kh_hi = wsb + 2 * (size_t)HEAD_ELEMS;
    __bf16* Kh_lo = wsb + 3 * (size_t)HEAD_ELEMS;
    __bf16* Vh    = wsb + 4 * (size_t)HEAD_ELEMS;
    float*  ctx   = (float*)(wsb + 5 * (size_t)HEAD_ELEMS);

    qkv_proj_kernel<<<dim3(32, 6, 3), 256, 0, stream>>>(
        q, k, v, Wq, bq, Wk, bk, Wv, bv,
        Qh_hi, Qh_lo, Kh_hi, Kh_lo, Vh);

    attn_fused_kernel<<<dim3(32, 12, 2), 256, 0, stream>>>(
        Qh_hi, Qh_lo, Kh_hi, Kh_lo, Vh, mask, ctx, wout);

    out_proj_kernel<<<dim3(32, 6, 1), 256, 0, stream>>>(ctx, Wo, bo, out);
}

// Round 6
// 686.913 us; speedup vs baseline: 1.4262x; 1.0175x over previous
//
#include <hip/hip_runtime.h>

typedef __bf16 bf16x8 __attribute__((ext_vector_type(8)));
typedef __bf16 bf16x4 __attribute__((ext_vector_type(4)));
typedef float  f32x4  __attribute__((ext_vector_type(4)));

#define MFMA_BF16(a, b, c) __builtin_amdgcn_mfma_f32_16x16x32_bf16((a), (b), (c), 0, 0, 0)

static constexpr int BATCH  = 2;
static constexpr int HEADS  = 12;
static constexpr int SEQ    = 2048;
static constexpr int DHEAD  = 64;
static constexpr int DMODEL = 768;
static constexpr int M_ROWS = BATCH * SEQ;                     // 4096
static constexpr int OUT_ELEMS  = M_ROWS * DMODEL;             // 3145728
static constexpr int HEAD_ELEMS = BATCH * HEADS * SEQ * DHEAD; // 3145728
static constexpr int W_ELEMS    = DMODEL * DMODEL;             // 589824

__device__ __forceinline__ void split_bf16(float x, __bf16 &hi, __bf16 &lo) {
    __bf16 h = (__bf16)x;
    hi = h;
    lo = (__bf16)(x - (float)h);
}

// ---------------------------------------------------------------------------
// K0: pre-split the four weight matrices to bf16 hi/lo ONCE.
// Removes the 32x-redundant per-block fp32->bf16 conversion from the GEMMs.
// grid: (W_ELEMS/4/256, 4) exact; z order: 0=Wq 1=Wk 2=Wv 3=Wo
// ---------------------------------------------------------------------------
__global__ __launch_bounds__(256) void wconv_kernel(
    const float* __restrict__ Wq, const float* __restrict__ Wk,
    const float* __restrict__ Wv, const float* __restrict__ Wo,
    __bf16* __restrict__ Whi, __bf16* __restrict__ Wlo)
{
    const int z = blockIdx.y;
    const float* W = (z == 0) ? Wq : (z == 1) ? Wk : (z == 2) ? Wv : Wo;
    __bf16* hi = Whi + (size_t)z * W_ELEMS;
    __bf16* lo = Wlo + (size_t)z * W_ELEMS;
    const int i = (blockIdx.x * 256 + threadIdx.x) * 4;
    float4 w4 = *(const float4*)&W[i];
    float wf[4] = {w4.x, w4.y, w4.z, w4.w};
    bf16x4 h4, l4;
    #pragma unroll
    for (int j = 0; j < 4; j++) {
        __bf16 h, l;
        split_bf16(wf[j], h, l);
        h4[j] = h; l4[j] = l;
    }
    *(bf16x4*)&hi[i] = h4;
    *(bf16x4*)&lo[i] = l4;
}

// ---------------------------------------------------------------------------
// K1: fused QKV projection.  out = X @ W.T + b, split to bf16 hi/lo.
// B (weights) now staged as pure bf16x8 copies from pre-split Whi/Wlo;
// only the A (activation) tile is converted in-loop.
//  z=0: Q (scaled 1/8) [b,h,s,d] hi+lo ; z=1: K [b,h,s,d] hi+lo ;
//  z=2: V transposed [b,h,d,s] hi only
// ---------------------------------------------------------------------------
__global__ __launch_bounds__(256) void qkv_proj_kernel(
    const float* __restrict__ qin, const float* __restrict__ kin, const float* __restrict__ vin,
    const __bf16* __restrict__ Whi, const __bf16* __restrict__ Wlo,
    const float* __restrict__ bq, const float* __restrict__ bk, const float* __restrict__ bv,
    __bf16* __restrict__ Qh_hi, __bf16* __restrict__ Qh_lo,
    __bf16* __restrict__ Kh_hi, __bf16* __restrict__ Kh_lo,
    __bf16* __restrict__ Vh)
{
    const int z = blockIdx.z;
    const float* X; const float* bias;
    float scale = 1.0f;
    if (z == 0)      { X = qin; bias = bq; scale = 0.125f; }
    else if (z == 1) { X = kin; bias = bk; }
    else             { X = vin; bias = bv; }
    const __bf16* Wh = Whi + (size_t)z * W_ELEMS;
    const __bf16* Wl = Wlo + (size_t)z * W_ELEMS;

    __shared__ __bf16 As_hi[128 * 40];
    __shared__ __bf16 As_lo[128 * 40];
    __shared__ __bf16 Bs_hi[128 * 40];
    __shared__ __bf16 Bs_lo[128 * 40];

    const int tid  = threadIdx.x;
    const int wid  = tid >> 6;
    const int lane = tid & 63;
    const int quad = lane >> 4;
    const int l15  = lane & 15;
    const int wm = (wid >> 1) * 64;
    const int wn = (wid & 1) * 64;
    const int mbase = blockIdx.x * 128;
    const int nbase = blockIdx.y * 128;

    const f32x4 zf = {0.f, 0.f, 0.f, 0.f};
    f32x4 acc[4][4];
    #pragma unroll
    for (int i = 0; i < 4; i++)
        #pragma unroll
        for (int j = 0; j < 4; j++) acc[i][j] = zf;

    for (int k0 = 0; k0 < DMODEL; k0 += 32) {
        // A tile: inline fp32 -> hi/lo split (X read once per N-block)
        #pragma unroll
        for (int i = 0; i < 4; i++) {
            int idx = i * 256 + tid;
            int r = idx >> 3;
            int c = (idx & 7) * 4;
            float4 a4 = *(const float4*)&X[(size_t)(mbase + r) * DMODEL + k0 + c];
            float af[4] = {a4.x, a4.y, a4.z, a4.w};
            bf16x4 ah4, al4;
            #pragma unroll
            for (int j = 0; j < 4; j++) {
                __bf16 hi, lo;
                split_bf16(af[j], hi, lo); ah4[j] = hi; al4[j] = lo;
            }
            *(bf16x4*)&As_hi[r * 40 + c] = ah4;
            *(bf16x4*)&As_lo[r * 40 + c] = al4;
        }
        // B tile: pure bf16x8 copies, no VALU
        #pragma unroll
        for (int i = 0; i < 2; i++) {
            int idx = i * 256 + tid;
            int r = idx >> 2;
            int c = (idx & 3) * 8;
            size_t g = (size_t)(nbase + r) * DMODEL + k0 + c;
            *(bf16x8*)&Bs_hi[r * 40 + c] = *(const bf16x8*)&Wh[g];
            *(bf16x8*)&Bs_lo[r * 40 + c] = *(const bf16x8*)&Wl[g];
        }
        __syncthreads();

        bf16x8 ah[4], al[4], bh[4], bl[4];
        #pragma unroll
        for (int f = 0; f < 4; f++) {
            int ra = (wm + f * 16 + l15) * 40 + quad * 8;
            ah[f] = *(const bf16x8*)&As_hi[ra];
            al[f] = *(const bf16x8*)&As_lo[ra];
            int rb = (wn + f * 16 + l15) * 40 + quad * 8;
            bh[f] = *(const bf16x8*)&Bs_hi[rb];
            bl[f] = *(const bf16x8*)&Bs_lo[rb];
        }
        #pragma unroll
        for (int fi = 0; fi < 4; fi++)
            #pragma unroll
            for (int fj = 0; fj < 4; fj++) {
                acc[fi][fj] = MFMA_BF16(ah[fi], bh[fj], acc[fi][fj]);
                acc[fi][fj] = MFMA_BF16(ah[fi], bl[fj], acc[fi][fj]);
                acc[fi][fj] = MFMA_BF16(al[fi], bh[fj], acc[fi][fj]);
            }
        __syncthreads();
    }

    float bvals[4];
    #pragma unroll
    for (int fj = 0; fj < 4; fj++)
        bvals[fj] = bias[nbase + wn + fj * 16 + l15];

    #pragma unroll
    for (int fi = 0; fi < 4; fi++)
        #pragma unroll
        for (int fj = 0; fj < 4; fj++)
            #pragma unroll
            for (int r = 0; r < 4; r++) {
                int m = mbase + wm + fi * 16 + quad * 4 + r;
                int n = nbase + wn + fj * 16 + l15;
                float val = (acc[fi][fj][r] + bvals[fj]) * scale;
                __bf16 hi, lo;
                split_bf16(val, hi, lo);
                int bb = m >> 11;
                int s  = m & (SEQ - 1);
                int hh = n >> 6;
                int d  = n & 63;
                int bh_ = bb * HEADS + hh;
                if (z == 0) {
                    size_t idx = ((size_t)bh_ * SEQ + s) * DHEAD + d;
                    Qh_hi[idx] = hi; Qh_lo[idx] = lo;
                } else if (z == 1) {
                    size_t idx = ((size_t)bh_ * SEQ + s) * DHEAD + d;
                    Kh_hi[idx] = hi; Kh_lo[idx] = lo;
                } else {
                    size_t idx = ((size_t)bh_ * DHEAD + d) * SEQ + s;
                    Vh[idx] = hi;
                }
            }
}

// ---------------------------------------------------------------------------
// K2: FUSED attention.  Phase 1 (ctx): per 64-key tile QK -> exp -> row-sums
// -> PV, accumulating ctx and per-row sums in registers.  Phase 2 (weights):
// inv = 1/lrun from registers, recompute QK^T+exp bit-identically and write
// normalized weight rows.  ctx is written as bf16 hi/lo (same bits out_proj
// would have produced by splitting f32 ctx) so out_proj stages conversion-free.
// ---------------------------------------------------------------------------
__global__ __launch_bounds__(256) void attn_fused_kernel(
    const __bf16* __restrict__ Qh_hi, const __bf16* __restrict__ Qh_lo,
    const __bf16* __restrict__ Kh_hi, const __bf16* __restrict__ Kh_lo,
    const __bf16* __restrict__ Vh,
    const float* __restrict__ mask,
    __bf16* __restrict__ ctx_hi, __bf16* __restrict__ ctx_lo, // [B,S,DMODEL]
    float* __restrict__ wout)      // [B,H,S,S]
{
    const int qt = blockIdx.x;
    const int h  = blockIdx.y;
    const int b  = blockIdx.z;
    const int bh = b * HEADS + h;

    const int tid  = threadIdx.x;
    const int wid  = tid >> 6;
    const int lane = tid & 63;
    const int quad = lane >> 4;
    const int l15  = lane & 15;
    const int qrow0 = qt * 64 + wid * 16;

    __shared__ __bf16 Ks_hi[64 * 72];
    __shared__ __bf16 Ks_lo[64 * 72];
    __shared__ __bf16 Vs[64 * 72];
    __shared__ __bf16 Ps[64 * 72];
    __shared__ float bias_s[SEQ];

    for (int i = tid; i < SEQ; i += 256)
        bias_s[i] = (mask[b * SEQ + i] != 0.0f) ? -1e30f : 0.0f;

    const __bf16* Kh_hi_b = Kh_hi + (size_t)bh * SEQ * DHEAD;
    const __bf16* Kh_lo_b = Kh_lo + (size_t)bh * SEQ * DHEAD;
    const __bf16* Vh_b    = Vh    + (size_t)bh * DHEAD * SEQ;

    // Q fragments for this wave's 16 rows (hi/lo, 64-d split in two 32-chunks)
    bf16x8 aqh[2], aql[2];
    #pragma unroll
    for (int ks = 0; ks < 2; ks++) {
        size_t off = ((size_t)bh * SEQ + qrow0 + l15) * DHEAD + ks * 32 + quad * 8;
        aqh[ks] = *(const bf16x8*)&Qh_hi[off];
        aql[ks] = *(const bf16x8*)&Qh_lo[off];
    }

    // per-thread staging coords
    const int sr = tid >> 3;          // 0..31
    const int sc = (tid & 7) * 8;     // 0..56
    bf16x8 skh[2], skl[2], sv[2];

    #pragma unroll
    for (int i = 0; i < 2; i++) {     // prologue: tile 0 -> regs
        int r = sr + i * 32;
        size_t gk = (size_t)r * DHEAD + sc;
        size_t gv = (size_t)r * SEQ + sc;
        skh[i] = *(const bf16x8*)&Kh_hi_b[gk];
        skl[i] = *(const bf16x8*)&Kh_lo_b[gk];
        sv[i]  = *(const bf16x8*)&Vh_b[gv];
    }

    const f32x4 zf = {0.f, 0.f, 0.f, 0.f};
    f32x4 cacc[4];
    #pragma unroll
    for (int fj = 0; fj < 4; fj++) cacc[fj] = zf;
    float lrun[4] = {};

    constexpr int NT = SEQ / 64;

    // ---------------- Phase 1: ctx + row sums ----------------
    for (int kt = 0; kt < NT; kt++) {
        const int k0 = kt * 64;

        #pragma unroll
        for (int i = 0; i < 2; i++) {
            int r = sr + i * 32;
            *(bf16x8*)&Ks_hi[r * 72 + sc] = skh[i];
            *(bf16x8*)&Ks_lo[r * 72 + sc] = skl[i];
            *(bf16x8*)&Vs[r * 72 + sc]    = sv[i];
        }
        __syncthreads();

        if (kt + 1 < NT) {
            const int kn = k0 + 64;
            #pragma unroll
            for (int i = 0; i < 2; i++) {
                int r = sr + i * 32;
                size_t gk = (size_t)(kn + r) * DHEAD + sc;
                size_t gv = (size_t)r * SEQ + kn + sc;
                skh[i] = *(const bf16x8*)&Kh_hi_b[gk];
                skl[i] = *(const bf16x8*)&Kh_lo_b[gk];
                sv[i]  = *(const bf16x8*)&Vh_b[gv];
            }
        }

        // QK^T (q pre-scaled by 1/8)
        f32x4 sacc[4];
        #pragma unroll
        for (int fj = 0; fj < 4; fj++) sacc[fj] = zf;

        #pragma unroll
        for (int ks = 0; ks < 2; ks++) {
            bf16x8 kh[4], kl[4];
            #pragma unroll
            for (int fj = 0; fj < 4; fj++) {
                int off = (fj * 16 + l15) * 72 + ks * 32 + quad * 8;
                kh[fj] = *(const bf16x8*)&Ks_hi[off];
                kl[fj] = *(const bf16x8*)&Ks_lo[off];
            }
            #pragma unroll
            for (int fj = 0; fj < 4; fj++) {
                sacc[fj] = MFMA_BF16(aqh[ks], kh[fj], sacc[fj]);
                sacc[fj] = MFMA_BF16(aqh[ks], kl[fj], sacc[fj]);
                sacc[fj] = MFMA_BF16(aql[ks], kh[fj], sacc[fj]);
            }
        }

        // p~ = exp(s + bias); bf16 p~ to this wave's Ps stripe, row sums
        float tsum[4] = {};
        #pragma unroll
        for (int fj = 0; fj < 4; fj++) {
            float bias = bias_s[k0 + fj * 16 + l15];
            #pragma unroll
            for (int r = 0; r < 4; r++) {
                float s = sacc[fj][r] + bias;
                s = fminf(s, 80.0f);
                float p = __expf(s);
                Ps[(wid * 16 + quad * 4 + r) * 72 + fj * 16 + l15] = (__bf16)p;
                tsum[r] += p;
            }
        }
        #pragma unroll
        for (int r = 0; r < 4; r++) {
            float t = tsum[r];
            t += __shfl_xor(t, 1);
            t += __shfl_xor(t, 2);
            t += __shfl_xor(t, 4);
            t += __shfl_xor(t, 8);
            lrun[r] += t;
        }

        // PV (plain bf16): A = this wave's Ps rows, B = Vs (V^T)
        #pragma unroll
        for (int ks = 0; ks < 2; ks++) {
            bf16x8 ph = *(const bf16x8*)&Ps[(wid * 16 + l15) * 72 + ks * 32 + quad * 8];
            #pragma unroll
            for (int fj = 0; fj < 4; fj++) {
                bf16x8 vh = *(const bf16x8*)&Vs[(fj * 16 + l15) * 72 + ks * 32 + quad * 8];
                cacc[fj] = MFMA_BF16(ph, vh, cacc[fj]);
            }
        }
        __syncthreads();
    }

    // inv from registers; ctx written as bf16 hi/lo
    float inv[4];
    #pragma unroll
    for (int r = 0; r < 4; r++) {
        int rl_ = quad * 4 + r;
        int row = qrow0 + rl_;
        inv[r] = 1.0f / lrun[r];
        #pragma unroll
        for (int fj = 0; fj < 4; fj++) {
            float val = cacc[fj][r] * inv[r];
            __bf16 hi, lo;
            split_bf16(val, hi, lo);
            size_t cidx = ((size_t)b * SEQ + row) * DMODEL + h * DHEAD + fj * 16 + l15;
            ctx_hi[cidx] = hi;
            ctx_lo[cidx] = lo;
        }
    }

    // ---------------- Phase 2: normalized weights ----------------
    #pragma unroll
    for (int i = 0; i < 2; i++) {
        int r = sr + i * 32;
        size_t gk = (size_t)r * DHEAD + sc;
        skh[i] = *(const bf16x8*)&Kh_hi_b[gk];
        skl[i] = *(const bf16x8*)&Kh_lo_b[gk];
    }

    for (int kt = 0; kt < NT; kt++) {
        const int k0 = kt * 64;

        #pragma unroll
        for (int i = 0; i < 2; i++) {
            int r = sr + i * 32;
            *(bf16x8*)&Ks_hi[r * 72 + sc] = skh[i];
            *(bf16x8*)&Ks_lo[r * 72 + sc] = skl[i];
        }
        __syncthreads();

        if (kt + 1 < NT) {
            const int kn = k0 + 64;
            #pragma unroll
            for (int i = 0; i < 2; i++) {
                int r = sr + i * 32;
                size_t gk = (size_t)(kn + r) * DHEAD + sc;
                skh[i] = *(const bf16x8*)&Kh_hi_b[gk];
                skl[i] = *(const bf16x8*)&Kh_lo_b[gk];
            }
        }

        f32x4 sacc[4];
        #pragma unroll
        for (int fj = 0; fj < 4; fj++) sacc[fj] = zf;

        #pragma unroll
        for (int ks = 0; ks < 2; ks++) {
            bf16x8 kh[4], kl[4];
            #pragma unroll
            for (int fj = 0; fj < 4; fj++) {
                int off = (fj * 16 + l15) * 72 + ks * 32 + quad * 8;
                kh[fj] = *(const bf16x8*)&Ks_hi[off];
                kl[fj] = *(const bf16x8*)&Ks_lo[off];
            }
            #pragma unroll
            for (int fj = 0; fj < 4; fj++) {
                sacc[fj] = MFMA_BF16(aqh[ks], kh[fj], sacc[fj]);
                sacc[fj] = MFMA_BF16(aqh[ks], kl[fj], sacc[fj]);
                sacc[fj] = MFMA_BF16(aql[ks], kh[fj], sacc[fj]);
            }
        }

        #pragma unroll
        for (int fj = 0; fj < 4; fj++) {
            float bias = bias_s[k0 + fj * 16 + l15];
            #pragma unroll
            for (int r = 0; r < 4; r++) {
                float s = sacc[fj][r] + bias;
                s = fminf(s, 80.0f);
                float p = __expf(s);
                int row = qrow0 + quad * 4 + r;
                wout[((size_t)bh * SEQ + row) * SEQ + k0 + fj * 16 + l15] = p * inv[r];
            }
        }
        __syncthreads();
    }
}

// ---------------------------------------------------------------------------
// K4: output projection: out = ctx @ Wo.T + bo  (f32 out).
// Both tiles staged as pure bf16x8 copies (ctx pre-split by attn, Wo by wconv).
// ---------------------------------------------------------------------------
__global__ __launch_bounds__(256) void out_proj_kernel(
    const __bf16* __restrict__ Xhi, const __bf16* __restrict__ Xlo,
    const __bf16* __restrict__ Whi, const __bf16* __restrict__ Wlo,
    const float* __restrict__ bias,
    float* __restrict__ out)
{
    __shared__ __bf16 As_hi[128 * 40];
    __shared__ __bf16 As_lo[128 * 40];
    __shared__ __bf16 Bs_hi[128 * 40];
    __shared__ __bf16 Bs_lo[128 * 40];

    const int tid  = threadIdx.x;
    const int wid  = tid >> 6;
    const int lane = tid & 63;
    const int quad = lane >> 4;
    const int l15  = lane & 15;
    const int wm = (wid >> 1) * 64;
    const int wn = (wid & 1) * 64;
    const int mbase = blockIdx.x * 128;
    const int nbase = blockIdx.y * 128;

    const f32x4 zf = {0.f, 0.f, 0.f, 0.f};
    f32x4 acc[4][4];
    #pragma unroll
    for (int i = 0; i < 4; i++)
        #pragma unroll
        for (int j = 0; j < 4; j++) acc[i][j] = zf;

    for (int k0 = 0; k0 < DMODEL; k0 += 32) {
        #pragma unroll
        for (int i = 0; i < 2; i++) {
            int idx = i * 256 + tid;
            int r = idx >> 2;
            int c = (idx & 3) * 8;
            size_t ga = (size_t)(mbase + r) * DMODEL + k0 + c;
            size_t gb = (size_t)(nbase + r) * DMODEL + k0 + c;
            *(bf16x8*)&As_hi[r * 40 + c] = *(const bf16x8*)&Xhi[ga];
            *(bf16x8*)&As_lo[r * 40 + c] = *(const bf16x8*)&Xlo[ga];
            *(bf16x8*)&Bs_hi[r * 40 + c] = *(const bf16x8*)&Whi[gb];
            *(bf16x8*)&Bs_lo[r * 40 + c] = *(const bf16x8*)&Wlo[gb];
        }
        __syncthreads();

        bf16x8 ah[4], al[4], bh[4], bl[4];
        #pragma unroll
        for (int f = 0; f < 4; f++) {
            int ra = (wm + f * 16 + l15) * 40 + quad * 8;
            ah[f] = *(const bf16x8*)&As_hi[ra];
            al[f] = *(const bf16x8*)&As_lo[ra];
            int rb = (wn + f * 16 + l15) * 40 + quad * 8;
            bh[f] = *(const bf16x8*)&Bs_hi[rb];
            bl[f] = *(const bf16x8*)&Bs_lo[rb];
        }
        #pragma unroll
        for (int fi = 0; fi < 4; fi++)
            #pragma unroll
            for (int fj = 0; fj < 4; fj++) {
                acc[fi][fj] = MFMA_BF16(ah[fi], bh[fj], acc[fi][fj]);
                acc[fi][fj] = MFMA_BF16(ah[fi], bl[fj], acc[fi][fj]);
                acc[fi][fj] = MFMA_BF16(al[fi], bh[fj], acc[fi][fj]);
            }
        __syncthreads();
    }

    float bvals[4];
    #pragma unroll
    for (int fj = 0; fj < 4; fj++)
        bvals[fj] = bias[nbase + wn + fj * 16 + l15];

    #pragma unroll
    for (int fi = 0; fi < 4; fi++)
        #pragma unroll
        for (int fj = 0; fj < 4; fj++)
            #pragma unroll
            for (int r = 0; r < 4; r++) {
                int m = mbase + wm + fi * 16 + quad * 4 + r;
                int n = nbase + wn + fj * 16 + l15;
                out[(size_t)m * DMODEL + n] = acc[fi][fj][r] + bvals[fj];
            }
}

// ---------------------------------------------------------------------------
extern "C" void kernel_launch(void* const* d_in, const int* in_sizes, int n_in,
                              void* d_out, int out_size, void* d_ws, size_t ws_size,
                              hipStream_t stream) {
    (void)in_sizes; (void)n_in; (void)out_size; (void)ws_size;

    const float* q    = (const float*)d_in[0];
    const float* k    = (const float*)d_in[1];
    const float* v    = (const float*)d_in[2];
    const float* mask = (const float*)d_in[3];
    const float* Wq   = (const float*)d_in[4];
    const float* bq   = (const float*)d_in[5];
    const float* Wk   = (const float*)d_in[6];
    const float* bk   = (const float*)d_in[7];
    const float* Wv   = (const float*)d_in[8];
    const float* bv   = (const float*)d_in[9];
    const float* Wo   = (const float*)d_in[10];
    const float* bo   = (const float*)d_in[11];

    float* out  = (float*)d_out;
    float* wout = out + (size_t)OUT_ELEMS;     // weights region of d_out

    // workspace layout (~53.5 MB):
    __bf16* wsb = (__bf16*)d_ws;
    __bf16* Qh_hi  = wsb;
    __bf16* Qh_lo  = wsb + 1 * (size_t)HEAD_ELEMS;
    __bf16* Kh_hi  = wsb + 2 * (size_t)HEAD_ELEMS;
    __bf16* Kh_lo  = wsb + 3 * (size_t)HEAD_ELEMS;
    __bf16* Vh     = wsb + 4 * (size_t)HEAD_ELEMS;
    __bf16* ctx_hi = wsb + 5 * (size_t)HEAD_ELEMS;
    __bf16* ctx_lo = ctx_hi + (size_t)OUT_ELEMS;
    __bf16* Whi    = ctx_lo + (size_t)OUT_ELEMS;          // [4][W_ELEMS]
    __bf16* Wlo    = Whi + 4 * (size_t)W_ELEMS;

    wconv_kernel<<<dim3(W_ELEMS / 4 / 256, 4), 256, 0, stream>>>(
        Wq, Wk, Wv, Wo, Whi, Wlo);

    qkv_proj_kernel<<<dim3(32, 6, 3), 256, 0, stream>>>(
        q, k, v, Whi, Wlo, bq, bk, bv,
        Qh_hi, Qh_lo, Kh_hi, Kh_lo, Vh);

    attn_fused_kernel<<<dim3(32, 12, 2), 256, 0, stream>>>(
        Qh_hi, Qh_lo, Kh_hi, Kh_lo, Vh, mask, ctx_hi, ctx_lo, wout);

    out_proj_kernel<<<dim3(32, 6, 1), 256, 0, stream>>>(
        ctx_hi, ctx_lo, Whi + 3 * (size_t)W_ELEMS, Wlo + 3 * (size_t)W_ELEMS, bo, out);
}